// Round 10
// baseline (1021.128 us; speedup 1.0000x reference)
//
#include <hip/hip_runtime.h>
#include <math.h>

// B=64, C=512, S=512, E=257, LK=128, HK=129.
// high_x is dead code in the reference: only low_x = attn(low,low,low)+attn(low,high,low).
//
// Pipeline (all heavy math on MFMA f16):
//  1. xcast: X f32 -> Xh f16 (aliases Kpack region; consumed by gemm_main before repack_K)
//  2. build_W: Wt[c][n] f16 = combined rfft+projection weight (512 -> 1028, pad 1152)
//  3. build_idt: iDt[n][k] f16 = irfft matrix matching OXh row layout [re264|im264]
//  4. gemm_main (MFMA f16): LHf = relu(x @ W + bias) * S_FOLD. 128x128, BK=32,
//     register-staged f16x8 (global_load_lds is BANNED: killed containers r7/r8).
//  5. repack_K: LHf -> Kpack in exact MFMA B-frag order (coalesced attention loads)
//  6. repack_V: LHf low -> Vpack (LDS transpose) in PV B-frag order
//  7. attn (MFMA f16 flash, DEFERRED PV): Q in chunk-linear LDS, P lane-linear,
//     f16 stats stride-18, 3 blocks/CU. Phase 1 is SOFTWARE-PIPELINED: chunk jt's
//     18 Kpack loads issue first, the softmax tail of chunk jt-1 runs under their
//     L2 latency, then the MFMAs consume the staged frags.
//  8. gemm_irfft (MFMA f16): out = OXh @ iDt. 128x128, K=544, register staging
//     with zero-padded tail step (OXh row ends at col 528).
//
// ws: LHf 69.2 MB + Kpack 75.5 MB (Xh alias) + Vpack 35.7 MB + Wt 1.2 MB + iDt 0.6 MB.

#define LD16 1056   // halves per LHf row: [lr 264 | li 264 | hr 264 | hi 264]
#define OXOFF 528   // OXh f16 output written into LHf[row][528..1056): [re 264 | im 264]

typedef __attribute__((ext_vector_type(4))) _Float16 f16x4;
typedef __attribute__((ext_vector_type(8))) _Float16 f16x8;
typedef __attribute__((ext_vector_type(4))) float f32x4;

#define S_FOLD 0.24975653f    // sqrt(1/sqrt(257))
#define INV_S  4.0039005f     // 1/S_FOLD
#define SC512  0.0441941738241592f   // 1/sqrt(512)

// ---------------- X f32 -> f16 ----------------

__global__ __launch_bounds__(256) void xcast(
    const float* __restrict__ X, _Float16* __restrict__ Xh) {
  const size_t total = (size_t)32768 * 512;
  size_t stride = (size_t)gridDim.x * 256 * 8;
  for (size_t idx = ((size_t)blockIdx.x * 256 + threadIdx.x) * 8; idx < total;
       idx += stride) {
    float4 a0 = *(const float4*)(X + idx);
    float4 a1 = *(const float4*)(X + idx + 4);
    f16x8 h = {(_Float16)a0.x, (_Float16)a0.y, (_Float16)a0.z, (_Float16)a0.w,
               (_Float16)a1.x, (_Float16)a1.y, (_Float16)a1.z, (_Float16)a1.w};
    *(f16x8*)(Xh + idx) = h;
  }
}

// ---------------- build combined rfft+projection weight, B-transposed ----------------
// Wt[c][n], c in [0,1152), n in [0,512). c>=1028 -> 0.

__global__ __launch_bounds__(256) void build_W(
    const float* __restrict__ l1r, const float* __restrict__ l1i,
    const float* __restrict__ h1r, const float* __restrict__ h1i,
    _Float16* __restrict__ Wt) {
  int c = blockIdx.x;
  int t = threadIdx.x;
  if (c >= 1028) {
    for (int n = t; n < 512; n += 256) Wt[(size_t)c * 512 + n] = (_Float16)0.0f;
    return;
  }
  __shared__ float Tc[512], Ts[512];
  __shared__ float wr[132], wi[132];
  for (int i = t; i < 512; i += 256) {
    float ang = (float)i * 0.0122718463030851f;  // 2*pi/512
    Tc[i] = cosf(ang);
    Ts[i] = sinf(ang);
  }
  int sub = (c >= 771) ? 3 : (c >= 514) ? 2 : (c >= 257) ? 1 : 0;
  int e = c - sub * 257;
  int Kn = (sub < 2) ? 128 : 129;
  int kb = (sub < 2) ? 0 : 128;
  if (t < Kn) {
    if (sub < 2) { wr[t] = l1r[t * 257 + e]; wi[t] = l1i[t * 257 + e]; }
    else         { wr[t] = h1r[t * 257 + e]; wi[t] = h1i[t * 257 + e]; }
  }
  __syncthreads();
  bool imag_out = (sub & 1);
  for (int n = t; n < 512; n += 256) {
    float acc = 0.f;
    for (int k = 0; k < Kn; ++k) {
      int kk = kb + k;
      int m = (n * kk) & 511;
      float Fr = Tc[m] * SC512;
      float Fi = -Ts[m] * SC512;
      if (!imag_out) acc += Fr * wr[k] - Fi * wi[k];
      else           acc += Fr * wi[k] + Fi * wr[k];
    }
    Wt[(size_t)c * 512 + n] = (_Float16)acc;
  }
}

// ---------------- build irfft matrix, B-transposed, matching OXh layout ----------------

__global__ __launch_bounds__(256) void build_idt(_Float16* __restrict__ iDt) {
  int idx = blockIdx.x * 256 + threadIdx.x;
  const int total = 512 * 544;
  if (idx >= total) return;
  int n = idx / 544;
  int k = idx - n * 544;
  float val = 0.f;
  if (k < 264) {
    int e = k;
    if (e <= 256) {
      float ce = (e == 0 || e == 256) ? 1.f : 2.f;
      int m = (n * e) & 511;
      val = ce * SC512 * cosf((float)m * 0.0122718463030851f);
    }
  } else if (k < 528) {
    int e = k - 264;
    if (e <= 256) {
      float ce = (e == 0 || e == 256) ? 1.f : 2.f;
      int m = (n * e) & 511;
      val = -ce * SC512 * sinf((float)m * 0.0122718463030851f);
    }
  }
  iDt[(size_t)n * 544 + k] = (_Float16)val;
}

// ---------------- MFMA f16 GEMM: LHf = relu(Xh @ W + bias) * S_FOLD ----------------
// M=32768, N=1152 (9 tiles of 128, c>=1028 discarded), K=512, BK=32.
// Block 256 (4 waves, 2x2); wave owns 64x64. Register-staged f16x8 LDS staging.

__global__ __launch_bounds__(256) void gemm_main(
    const _Float16* __restrict__ Xh, const _Float16* __restrict__ Wt,
    const float* __restrict__ lbr, const float* __restrict__ lbi,
    const float* __restrict__ hbr, const float* __restrict__ hbi,
    _Float16* __restrict__ LHf) {
  __shared__ __align__(16) _Float16 As[128 * 32];
  __shared__ __align__(16) _Float16 Bs[128 * 32];

  int t = threadIdx.x;
  int w = t >> 6, L = t & 63, q = L >> 4, lc = L & 15;
  int wr = w >> 1, wc = w & 1;
  int row0 = blockIdx.y * 128;
  int n0 = blockIdx.x * 128;

  int sr = t >> 2, sc = (t & 3) * 8;  // staging: row 0..63, col 0/8/16/24

  f32x4 acc[4][4];
#pragma unroll
  for (int i = 0; i < 4; ++i)
#pragma unroll
    for (int j = 0; j < 4; ++j) acc[i][j] = f32x4{0.f, 0.f, 0.f, 0.f};

  for (int k0 = 0; k0 < 512; k0 += 32) {
    // stage A/B: 128 rows x 32 halves each, f16x8 per lane, 2 rows apart by 64
    f16x8 a0 = *(const f16x8*)(Xh + (size_t)(row0 + sr) * 512 + k0 + sc);
    f16x8 a1 = *(const f16x8*)(Xh + (size_t)(row0 + sr + 64) * 512 + k0 + sc);
    f16x8 b0 = *(const f16x8*)(Wt + (size_t)(n0 + sr) * 512 + k0 + sc);
    f16x8 b1 = *(const f16x8*)(Wt + (size_t)(n0 + sr + 64) * 512 + k0 + sc);
    *(f16x8*)(As + sr * 32 + sc) = a0;
    *(f16x8*)(As + (sr + 64) * 32 + sc) = a1;
    *(f16x8*)(Bs + sr * 32 + sc) = b0;
    *(f16x8*)(Bs + (sr + 64) * 32 + sc) = b1;
    __syncthreads();

    f16x8 af[4], bf[4];
#pragma unroll
    for (int m = 0; m < 4; ++m)
      af[m] = *(const f16x8*)(As + (wr * 64 + m * 16 + lc) * 32 + q * 8);
#pragma unroll
    for (int n = 0; n < 4; ++n)
      bf[n] = *(const f16x8*)(Bs + (wc * 64 + n * 16 + lc) * 32 + q * 8);
#pragma unroll
    for (int m = 0; m < 4; ++m)
#pragma unroll
      for (int n = 0; n < 4; ++n)
        acc[m][n] = __builtin_amdgcn_mfma_f32_16x16x32_f16(af[m], bf[n], acc[m][n], 0, 0, 0);
    __syncthreads();
  }

  // epilogue: direct scalar f16 writes with bias+relu+scale (c<1028 guard)
#pragma unroll
  for (int m = 0; m < 4; ++m) {
#pragma unroll
    for (int ns = 0; ns < 4; ++ns) {
      int c = n0 + wc * 64 + ns * 16 + lc;
      if (c < 1028) {
        int sub = (c >= 771) ? 3 : (c >= 514) ? 2 : (c >= 257) ? 1 : 0;
        int e = c - sub * 257;
        float bv = (sub == 0) ? lbr[e] : (sub == 1) ? lbi[e] : (sub == 2) ? hbr[e] : hbi[e];
#pragma unroll
        for (int r = 0; r < 4; ++r) {
          int row = row0 + wr * 64 + m * 16 + q * 4 + r;
          float val = fmaxf(acc[m][ns][r] + bv, 0.f) * S_FOLD;
          LHf[(size_t)row * LD16 + sub * 264 + e] = (_Float16)val;
        }
      }
    }
  }
}

// ---------------- repack K into MFMA B-frag-linear order ----------------

__global__ __launch_bounds__(256) void repack_K(
    const _Float16* __restrict__ LHf, _Float16* __restrict__ Kpack) {
  int t = threadIdx.x;
  int w = t >> 6, L = t & 63, q = L >> 4, lc = L & 15;
  int wc = blockIdx.x * 4 + w;
  int ec = wc % 9;
  int tmp = wc / 9;
  int jt = tmp & 31; tmp >>= 5;
  int comp = tmp & 1; tmp >>= 1;
  int pass = tmp & 1;
  int b = tmp >> 1;
  f16x8 v;
  if (ec == 8 && q > 0) {
    v = f16x8{(_Float16)0, (_Float16)0, (_Float16)0, (_Float16)0,
              (_Float16)0, (_Float16)0, (_Float16)0, (_Float16)0};
  } else {
    v = *(const f16x8*)(LHf + (size_t)(b * 512 + jt * 16 + lc) * LD16 +
                        pass * 528 + comp * 264 + ec * 32 + q * 8);
  }
  *(f16x8*)(Kpack + (size_t)wc * 512 + L * 8) = v;
}

// ---------------- repack V (low) into PV B-frag order via LDS transpose ----------------

__global__ __launch_bounds__(256) void repack_V(
    const _Float16* __restrict__ LHf, _Float16* __restrict__ Vpack) {
  int bid = blockIdx.x;
  int et = bid % 17;
  int tmp = bid / 17;
  int comp = tmp & 1;
  int b = tmp >> 1;
  int t = threadIdx.x;
  __shared__ __align__(16) _Float16 tile[512 * 16];

  const f16x8 zero8 = {(_Float16)0, (_Float16)0, (_Float16)0, (_Float16)0,
                       (_Float16)0, (_Float16)0, (_Float16)0, (_Float16)0};
  for (int j = t; j < 512; j += 256) {
    const _Float16* src = LHf + (size_t)(b * 512 + j) * LD16 + comp * 264 + et * 16;
    f16x8 v0, v1;
    if (et < 16) {
      v0 = *(const f16x8*)(src);
      v1 = *(const f16x8*)(src + 8);
    } else {
      v0 = *(const f16x8*)(src);
      v1 = zero8;
    }
    *(f16x8*)(tile + j * 16) = v0;
    *(f16x8*)(tile + j * 16 + 8) = v1;
  }
  __syncthreads();

#pragma unroll
  for (int it = 0; it < 4; ++it) {
    int c2 = it * 256 + t;
    int ks = c2 >> 6;
    int L2 = c2 & 63;
    int q2 = L2 >> 4, lc2 = L2 & 15;
    f16x8 v;
#pragma unroll
    for (int i = 0; i < 8; ++i) v[i] = tile[(ks * 32 + q2 * 8 + i) * 16 + lc2];
    *(f16x8*)(Vpack + ((((size_t)(b * 2 + comp) * 17 + et) * 16 + ks) * 512) + L2 * 8) = v;
  }
}

// ---------------- DPP 16-lane reductions (VALU pipe, no DS latency) ----------------

template <int CTRL>
__device__ __forceinline__ float dpp_f32(float x) {
  return __int_as_float(
      __builtin_amdgcn_update_dpp(0, __float_as_int(x), CTRL, 0xF, 0xF, true));
}

__device__ __forceinline__ float red_max16(float x) {
  x = fmaxf(x, dpp_f32<0xB1>(x));
  x = fmaxf(x, dpp_f32<0x4E>(x));
  x = fmaxf(x, dpp_f32<0x141>(x));
  x = fmaxf(x, dpp_f32<0x140>(x));
  return x;
}

__device__ __forceinline__ float red_sum16(float x) {
  x += dpp_f32<0xB1>(x);
  x += dpp_f32<0x4E>(x);
  x += dpp_f32<0x141>(x);
  x += dpp_f32<0x140>(x);
  return x;
}

// ---------------- MFMA f16 flash attention, DEFERRED PV, 3 blocks/CU ----------------
// Phase 1 software-pipelined: chunk jt's 18 Kpack loads are issued into registers,
// then the softmax TAIL of chunk jt-1 runs (DPP+exp VALU, ~200cy) hiding the L2
// latency, then the MFMAs consume the staged frags. Score regs are reused across
// the pipeline (tail consumes, then re-zeroed for accumulation): +72 VGPR for the
// staged K frags, est ~155 total, under the 3-block cap of 170.

__global__ __launch_bounds__(256, 3) void attn_mfma3(
    const _Float16* __restrict__ LHf, const _Float16* __restrict__ Kpack,
    const _Float16* __restrict__ Vpack, _Float16* __restrict__ OXh) {
  int bid = blockIdx.x;
  int xcd = bid & 7;
  int ix = bid >> 3;
  int rt = ix & 31;
  int b = xcd + 8 * (ix >> 5);
  int t = threadIdx.x;
  int w = t >> 6, L = t & 63, q = L >> 4, lc = L & 15;

  __shared__ __align__(16) _Float16 sQc[2][8][64][8];      // 16384 B
  __shared__ __align__(16) _Float16 sP2[2][16][4][16][8];  // 32768 B
  __shared__ __align__(16) _Float16 sM[2][32][18];         // 2304 B
  __shared__ __align__(16) _Float16 sS[2][32][18];         // 2304 B

  const f16x8 zero8 = {(_Float16)0, (_Float16)0, (_Float16)0, (_Float16)0,
                       (_Float16)0, (_Float16)0, (_Float16)0, (_Float16)0};

  // fill sQc (chunk-linear: lane L owns slot [comp][ec][L]) + Qf8 in regs
  const _Float16* qbase = LHf + (size_t)(b * 512 + rt * 16 + lc) * LD16;
  f16x8 Qf8[2];
#pragma unroll
  for (int comp = 0; comp < 2; ++comp)
    Qf8[comp] = (q == 0) ? *(const f16x8*)(qbase + comp * 264 + 256) : zero8;
  for (int g = w; g < 16; g += 4) {
    int comp = g >> 3, ec = g & 7;
    f16x8 v = *(const f16x8*)(qbase + comp * 264 + ec * 32 + q * 8);
    *(f16x8*)(&sQc[comp][ec][L][0]) = v;
  }
  __syncthreads();

  int t0 = (w == 0) ? 0 : (4 * w + 1);   // et tiles {0..4},{5..8},{9..12},{13..16}
  int nt = (w == 0) ? 5 : 4;
  int h = q >> 1;

  f32x4 accR[5], accI[5];  // final normalized outputs, accumulated across passes
#pragma unroll
  for (int i = 0; i < 5; ++i) {
    accR[i] = f32x4{0.f, 0.f, 0.f, 0.f};
    accI[i] = f32x4{0.f, 0.f, 0.f, 0.f};
  }

  for (int pass = 0; pass < 2; ++pass) {
    // softmax tail for chunk jtc's scores (writes sP2/sM/sS; per-wave regions disjoint)
    auto tail = [&](int jtc, f32x4& tRR, f32x4& tII, f32x4& tRI, f32x4& tIR) {
      int jj = (jtc * 4 + w) * 16 + lc;
      int ksw = jj >> 5, qw = (jj >> 3) & 3, iw = jj & 7;
      int jtile = jtc * 4 + w;
#pragma unroll
      for (int r = 0; r < 4; ++r) {
        float vr = tRR[r] - tII[r];
        float vi = tRI[r] + tIR[r];
        _Float16 mlrh = (_Float16)red_max16(vr);
        _Float16 mlih = (_Float16)red_max16(vi);
        float mlr = (float)mlrh;
        float mli = (float)mlih;
        float ur = __expf(vr - mlr);
        float ui = __expf(vi - mli);
        int row = q * 4 + r;
        sP2[0][ksw][qw][row][iw] = (_Float16)ur;
        sP2[1][ksw][qw][row][iw] = (_Float16)ui;
        float sr = red_sum16(ur);
        float si = red_sum16(ui);
        if (lc == 0) {
          sM[0][jtile][row] = mlrh;
          sS[0][jtile][row] = (_Float16)sr;
          sM[1][jtile][row] = mlih;
          sS[1][jtile][row] = (_Float16)si;
        }
      }
    };

    // ========= phase 1: software-pipelined QK + local softmax, no barriers ======
    f32x4 sRR, sII, sRI, sIR;  // live scores; consumed by deferred tail next iter
    for (int jt = 0; jt < 8; ++jt) {
      size_t kb0 = ((((size_t)(b * 2 + pass) * 2 + 0) * 32 + (jt * 4 + w)) * 9) * 512;
      size_t kb1 = ((((size_t)(b * 2 + pass) * 2 + 1) * 32 + (jt * 4 + w)) * 9) * 512;
      // issue this chunk's 18 K-frag loads into registers
      f16x8 kr[9], ki[9];
#pragma unroll
      for (int ec = 0; ec < 9; ++ec) {
        kr[ec] = *(const f16x8*)(Kpack + kb0 + (size_t)ec * 512 + L * 8);
        ki[ec] = *(const f16x8*)(Kpack + kb1 + (size_t)ec * 512 + L * 8);
      }
      // previous chunk's softmax tail runs under the load latency
      if (jt > 0) tail(jt - 1, sRR, sII, sRI, sIR);
      sRR = f32x4{0.f, 0.f, 0.f, 0.f};
      sII = f32x4{0.f, 0.f, 0.f, 0.f};
      sRI = f32x4{0.f, 0.f, 0.f, 0.f};
      sIR = f32x4{0.f, 0.f, 0.f, 0.f};
      __builtin_amdgcn_s_setprio(1);
#pragma unroll
      for (int ec = 0; ec < 8; ++ec) {
        f16x8 q0 = *(const f16x8*)(&sQc[0][ec][L][0]);
        f16x8 q1 = *(const f16x8*)(&sQc[1][ec][L][0]);
        sRR = __builtin_amdgcn_mfma_f32_16x16x32_f16(q0, kr[ec], sRR, 0, 0, 0);
        sII = __builtin_amdgcn_mfma_f32_16x16x32_f16(q1, ki[ec], sII, 0, 0, 0);
        sRI = __builtin_amdgcn_mfma_f32_16x16x32_f16(q0, ki[ec], sRI, 0, 0, 0);
        sIR = __builtin_amdgcn_mfma_f32_16x16x32_f16(q1, kr[ec], sIR, 0, 0, 0);
      }
      {  // ec == 8 (Q fragment in registers)
        sRR = __builtin_amdgcn_mfma_f32_16x16x32_f16(Qf8[0], kr[8], sRR, 0, 0, 0);
        sII = __builtin_amdgcn_mfma_f32_16x16x32_f16(Qf8[1], ki[8], sII, 0, 0, 0);
        sRI = __builtin_amdgcn_mfma_f32_16x16x32_f16(Qf8[0], ki[8], sRI, 0, 0, 0);
        sIR = __builtin_amdgcn_mfma_f32_16x16x32_f16(Qf8[1], kr[8], sIR, 0, 0, 0);
      }
      __builtin_amdgcn_s_setprio(0);
    }
    tail(7, sRR, sII, sRI, sIR);
    __syncthreads();  // P + stats published

    // ================= stat merge for row lc (conflict-free scalar reads) =======
    float mfR = -3.0e38f, mfI = -3.0e38f;
#pragma unroll
    for (int j = 0; j < 32; ++j) {
      mfR = fmaxf(mfR, (float)sM[0][j][lc]);
      mfI = fmaxf(mfI, (float)sM[1][j][lc]);
    }
    float lR = 0.f, lI = 0.f;
#pragma unroll
    for (int j = 0; j < 32; ++j) {
      lR += (float)sS[0][j][lc] * __expf((float)sM[0][j][lc] - mfR);
      lI += (float)sS[1][j][lc] * __expf((float)sM[1][j][lc] - mfI);
    }
    float gRb = INV_S / lR;
    float gIb = INV_S / lI;

    // ================= PV: pre-normalized A-frags, 2 accs, no barriers =========
    for (int ks = 0; ks < 16; ++ks) {
      int jtA = ks * 2 + h;
      float gR = __expf((float)sM[0][jtA][lc] - mfR) * gRb;
      float gI = __expf((float)sM[1][jtA][lc] - mfI) * gIb;
      f16x8 uR = *(const f16x8*)&sP2[0][ks][q][lc][0];
      f16x8 uI = *(const f16x8*)&sP2[1][ks][q][lc][0];
      _Float16 hR = (_Float16)gR;
      _Float16 hI = (_Float16)gI;
      _Float16 hmI = (_Float16)(-gI);
      f16x8 aR, aI, amI;
#pragma unroll
      for (int i = 0; i < 8; ++i) {
        aR[i] = uR[i] * hR;
        aI[i] = uI[i] * hI;
        amI[i] = uI[i] * hmI;
      }
      __builtin_amdgcn_s_setprio(1);
#pragma unroll
      for (int ti = 0; ti < 5; ++ti) {
        if (ti < nt) {
          int et = t0 + ti;
          size_t vb = (((size_t)(b * 2 + 0) * 17 + et) * 16 + ks) * 512;
          size_t vb2 = (((size_t)(b * 2 + 1) * 17 + et) * 16 + ks) * 512;
          f16x8 bVr = *(const f16x8*)(Vpack + vb + L * 8);
          f16x8 bVi = *(const f16x8*)(Vpack + vb2 + L * 8);
          accR[ti] = __builtin_amdgcn_mfma_f32_16x16x32_f16(aR, bVr, accR[ti], 0, 0, 0);
          accR[ti] = __builtin_amdgcn_mfma_f32_16x16x32_f16(amI, bVi, accR[ti], 0, 0, 0);
          accI[ti] = __builtin_amdgcn_mfma_f32_16x16x32_f16(aR, bVi, accI[ti], 0, 0, 0);
          accI[ti] = __builtin_amdgcn_mfma_f32_16x16x32_f16(aI, bVr, accI[ti], 0, 0, 0);
        }
      }
      __builtin_amdgcn_s_setprio(0);
    }
    __syncthreads();  // sP2/sM/sS reused by next pass's phase 1
  }

  // ---- store OXh f16 rows into LHf[.][528..1056) ----
  _Float16* obase = OXh + (size_t)(b * 512 + rt * 16) * LD16 + OXOFF;
#pragma unroll
  for (int ti = 0; ti < 5; ++ti) {
    if (ti < nt) {
      int e = (t0 + ti) * 16 + lc;
      if (e < 257) {
#pragma unroll
        for (int r = 0; r < 4; ++r) {
          _Float16* dst = obase + (size_t)(q * 4 + r) * LD16;
          dst[e] = (_Float16)accR[ti][r];
          dst[264 + e] = (_Float16)accI[ti][r];
        }
      }
    }
  }
}

// ---------------- MFMA f16 GEMM: out = OXh @ iDt ----------------
// M=32768, N=512 (4 tiles of 128), K=544 (OXh pad). Register-staged f16x8;
// zero-padded tail for cols 528..543.

__global__ __launch_bounds__(256) void gemm_irfft(
    const _Float16* __restrict__ LHf, const _Float16* __restrict__ iDt,
    float* __restrict__ out) {
  __shared__ __align__(16) _Float16 As[128 * 32];
  __shared__ __align__(16) _Float16 Bs[128 * 32];

  int t = threadIdx.x;
  int w = t >> 6, L = t & 63, q = L >> 4, lc = L & 15;
  int wr = w >> 1, wc = w & 1;
  int row0 = blockIdx.y * 128;
  int n0 = blockIdx.x * 128;

  int sr = t >> 2, sc = (t & 3) * 8;

  const f16x8 zero8 = {(_Float16)0, (_Float16)0, (_Float16)0, (_Float16)0,
                       (_Float16)0, (_Float16)0, (_Float16)0, (_Float16)0};

  f32x4 acc[4][4];
#pragma unroll
  for (int i = 0; i < 4; ++i)
#pragma unroll
    for (int j = 0; j < 4; ++j) acc[i][j] = f32x4{0.f, 0.f, 0.f, 0.f};

  for (int k0 = 0; k0 < 544; k0 += 32) {
    // A: OXh rows, valid cols < 528 (tail cols 528..543 zero-padded)
    f16x8 a0, a1;
    if (k0 + sc < 528) {
      a0 = *(const f16x8*)(LHf + (size_t)(row0 + sr) * LD16 + OXOFF + k0 + sc);
      a1 = *(const f16x8*)(LHf + (size_t)(row0 + sr + 64) * LD16 + OXOFF + k0 + sc);
    } else {
      a0 = zero8; a1 = zero8;
    }
    f16x8 b0 = *(const f16x8*)(iDt + (size_t)(n0 + sr) * 544 + k0 + sc);
    f16x8 b1 = *(const f16x8*)(iDt + (size_t)(n0 + sr + 64) * 544 + k0 + sc);
    *(f16x8*)(As + sr * 32 + sc) = a0;
    *(f16x8*)(As + (sr + 64) * 32 + sc) = a1;
    *(f16x8*)(Bs + sr * 32 + sc) = b0;
    *(f16x8*)(Bs + (sr + 64) * 32 + sc) = b1;
    __syncthreads();

    f16x8 af[4], bf[4];
#pragma unroll
    for (int m = 0; m < 4; ++m)
      af[m] = *(const f16x8*)(As + (wr * 64 + m * 16 + lc) * 32 + q * 8);
#pragma unroll
    for (int n = 0; n < 4; ++n)
      bf[n] = *(const f16x8*)(Bs + (wc * 64 + n * 16 + lc) * 32 + q * 8);
#pragma unroll
    for (int m = 0; m < 4; ++m)
#pragma unroll
      for (int n = 0; n < 4; ++n)
        acc[m][n] = __builtin_amdgcn_mfma_f32_16x16x32_f16(af[m], bf[n], acc[m][n], 0, 0, 0);
    __syncthreads();
  }

#pragma unroll
  for (int m = 0; m < 4; ++m)
#pragma unroll
    for (int ns = 0; ns < 4; ++ns) {
      int c = n0 + wc * 64 + ns * 16 + lc;
#pragma unroll
      for (int r = 0; r < 4; ++r) {
        int row = row0 + wr * 64 + m * 16 + q * 4 + r;
        out[(size_t)row * 512 + c] = acc[m][ns][r];
      }
    }
}

// ---------------- launch ----------------

extern "C" void kernel_launch(void* const* d_in, const int* in_sizes, int n_in,
                              void* d_out, int out_size, void* d_ws, size_t ws_size,
                              hipStream_t stream) {
  const float* x   = (const float*)d_in[0];
  const float* l1r = (const float*)d_in[1];
  const float* l1i = (const float*)d_in[2];
  const float* h1r = (const float*)d_in[3];
  const float* h1i = (const float*)d_in[4];
  const float* lbr = (const float*)d_in[5];
  const float* lbi = (const float*)d_in[6];
  const float* hbr = (const float*)d_in[7];
  const float* hbi = (const float*)d_in[8];
  float* out = (float*)d_out;

  _Float16* ws = (_Float16*)d_ws;
  size_t off = 0;
  _Float16* LHf = ws + off;   off += (size_t)32768 * LD16;        // 69.2 MB
  _Float16* Kpack = ws + off; off += (size_t)73728 * 512;         // 75.5 MB
  _Float16* Vpack = ws + off; off += (size_t)64 * 2 * 17 * 16 * 512;  // 35.7 MB
  _Float16* Wt = ws + off;    off += (size_t)1152 * 512;          // 1.2 MB
  _Float16* iDt = ws + off;   off += (size_t)512 * 544;           // 0.6 MB
  _Float16* Xh = Kpack;  // alias: consumed by gemm_main before repack_K overwrites

  hipMemsetAsync(LHf, 0, (size_t)32768 * LD16 * 2, stream);

  xcast<<<2048, 256, 0, stream>>>(x, Xh);
  build_W<<<1152, 256, 0, stream>>>(l1r, l1i, h1r, h1i, Wt);
  build_idt<<<(512 * 544 + 255) / 256, 256, 0, stream>>>(iDt);

  gemm_main<<<dim3(9, 256), 256, 0, stream>>>(Xh, Wt, lbr, lbi, hbr, hbi, LHf);
  repack_K<<<73728 / 4, 256, 0, stream>>>(LHf, Kpack);
  repack_V<<<64 * 2 * 17, 256, 0, stream>>>(LHf, Vpack);
  attn_mfma3<<<2048, 256, 0, stream>>>(LHf, Kpack, Vpack, LHf);
  gemm_irfft<<<dim3(4, 256), 256, 0, stream>>>(LHf, iDt, out);
}

// Round 11
// 966.407 us; speedup vs baseline: 1.0566x; 1.0566x over previous
//
#include <hip/hip_runtime.h>
#include <math.h>

// B=64, C=512, S=512, E=257, LK=128, HK=129.
// high_x is dead code in the reference: only low_x = attn(low,low,low)+attn(low,high,low).
//
// Pipeline (all heavy math on MFMA f16):
//  1. pad_zero: zero the 28 pad halves per LHf row (replaces 69MB memset)
//  2. xcast: X f32 -> Xh f16 (aliases Kpack region; consumed before repack_K)
//  3. build_W / build_idt: weights
//  4. gemm_main (MFMA f16): 128x128, BK=32, register-staged f16x8
//     (global_load_lds BANNED: killed containers r7/r8)
//  5. repack_K / repack_V
//  6. attn: DEFERRED PV, 3 blocks/CU. Phase 1 software-pipelined with 18 NAMED
//     f16x8 staging regs (rule #20: arrays+lambda went to scratch in r10 -> 1.3GB
//     scratch writes; named scalars + plain inline fn force register allocation).
//  7. gemm_irfft (MFMA f16): 128x128, K=544, zero-padded tail.
//
// ws: LHf 69.2 MB + Kpack 75.5 MB (Xh alias) + Vpack 35.7 MB + Wt 1.2 MB + iDt 0.6 MB.

#define LD16 1056   // halves per LHf row: [lr 264 | li 264 | hr 264 | hi 264]
#define OXOFF 528   // OXh f16 output written into LHf[row][528..1056): [re 264 | im 264]

typedef __attribute__((ext_vector_type(4))) _Float16 f16x4;
typedef __attribute__((ext_vector_type(8))) _Float16 f16x8;
typedef __attribute__((ext_vector_type(4))) float f32x4;

#define S_FOLD 0.24975653f    // sqrt(1/sqrt(257))
#define INV_S  4.0039005f     // 1/S_FOLD
#define SC512  0.0441941738241592f   // 1/sqrt(512)

// ---------------- zero only the pad columns of LHf ----------------
// Pads: e=257..263 within each 264-wide sub-block (4 sub-blocks per row).
// These are the ONLY bytes the old full memset protected: read by repack_K/V
// (ec==8 / et==16 paths), sQc/Qf8 loads, and gemm_irfft's OXh A-reads.

__global__ __launch_bounds__(256) void pad_zero(_Float16* __restrict__ LHf) {
  int row = blockIdx.x * 256 + threadIdx.x;
  _Float16* p = LHf + (size_t)row * LD16;
#pragma unroll
  for (int sub = 0; sub < 4; ++sub)
#pragma unroll
    for (int e = 257; e < 264; ++e) p[sub * 264 + e] = (_Float16)0;
}

// ---------------- X f32 -> f16 ----------------

__global__ __launch_bounds__(256) void xcast(
    const float* __restrict__ X, _Float16* __restrict__ Xh) {
  const size_t total = (size_t)32768 * 512;
  size_t stride = (size_t)gridDim.x * 256 * 8;
  for (size_t idx = ((size_t)blockIdx.x * 256 + threadIdx.x) * 8; idx < total;
       idx += stride) {
    float4 a0 = *(const float4*)(X + idx);
    float4 a1 = *(const float4*)(X + idx + 4);
    f16x8 h = {(_Float16)a0.x, (_Float16)a0.y, (_Float16)a0.z, (_Float16)a0.w,
               (_Float16)a1.x, (_Float16)a1.y, (_Float16)a1.z, (_Float16)a1.w};
    *(f16x8*)(Xh + idx) = h;
  }
}

// ---------------- build combined rfft+projection weight, B-transposed ----------------
// Wt[c][n], c in [0,1152), n in [0,512). c>=1028 -> 0.

__global__ __launch_bounds__(256) void build_W(
    const float* __restrict__ l1r, const float* __restrict__ l1i,
    const float* __restrict__ h1r, const float* __restrict__ h1i,
    _Float16* __restrict__ Wt) {
  int c = blockIdx.x;
  int t = threadIdx.x;
  if (c >= 1028) {
    for (int n = t; n < 512; n += 256) Wt[(size_t)c * 512 + n] = (_Float16)0.0f;
    return;
  }
  __shared__ float Tc[512], Ts[512];
  __shared__ float wr[132], wi[132];
  for (int i = t; i < 512; i += 256) {
    float ang = (float)i * 0.0122718463030851f;  // 2*pi/512
    Tc[i] = cosf(ang);
    Ts[i] = sinf(ang);
  }
  int sub = (c >= 771) ? 3 : (c >= 514) ? 2 : (c >= 257) ? 1 : 0;
  int e = c - sub * 257;
  int Kn = (sub < 2) ? 128 : 129;
  int kb = (sub < 2) ? 0 : 128;
  if (t < Kn) {
    if (sub < 2) { wr[t] = l1r[t * 257 + e]; wi[t] = l1i[t * 257 + e]; }
    else         { wr[t] = h1r[t * 257 + e]; wi[t] = h1i[t * 257 + e]; }
  }
  __syncthreads();
  bool imag_out = (sub & 1);
  for (int n = t; n < 512; n += 256) {
    float acc = 0.f;
    for (int k = 0; k < Kn; ++k) {
      int kk = kb + k;
      int m = (n * kk) & 511;
      float Fr = Tc[m] * SC512;
      float Fi = -Ts[m] * SC512;
      if (!imag_out) acc += Fr * wr[k] - Fi * wi[k];
      else           acc += Fr * wi[k] + Fi * wr[k];
    }
    Wt[(size_t)c * 512 + n] = (_Float16)acc;
  }
}

// ---------------- build irfft matrix, B-transposed, matching OXh layout ----------------

__global__ __launch_bounds__(256) void build_idt(_Float16* __restrict__ iDt) {
  int idx = blockIdx.x * 256 + threadIdx.x;
  const int total = 512 * 544;
  if (idx >= total) return;
  int n = idx / 544;
  int k = idx - n * 544;
  float val = 0.f;
  if (k < 264) {
    int e = k;
    if (e <= 256) {
      float ce = (e == 0 || e == 256) ? 1.f : 2.f;
      int m = (n * e) & 511;
      val = ce * SC512 * cosf((float)m * 0.0122718463030851f);
    }
  } else if (k < 528) {
    int e = k - 264;
    if (e <= 256) {
      float ce = (e == 0 || e == 256) ? 1.f : 2.f;
      int m = (n * e) & 511;
      val = -ce * SC512 * sinf((float)m * 0.0122718463030851f);
    }
  }
  iDt[(size_t)n * 544 + k] = (_Float16)val;
}

// ---------------- MFMA f16 GEMM: LHf = relu(Xh @ W + bias) * S_FOLD ----------------
// M=32768, N=1152 (9 tiles of 128, c>=1028 discarded), K=512, BK=32.

__global__ __launch_bounds__(256) void gemm_main(
    const _Float16* __restrict__ Xh, const _Float16* __restrict__ Wt,
    const float* __restrict__ lbr, const float* __restrict__ lbi,
    const float* __restrict__ hbr, const float* __restrict__ hbi,
    _Float16* __restrict__ LHf) {
  __shared__ __align__(16) _Float16 As[128 * 32];
  __shared__ __align__(16) _Float16 Bs[128 * 32];

  int t = threadIdx.x;
  int w = t >> 6, L = t & 63, q = L >> 4, lc = L & 15;
  int wr = w >> 1, wc = w & 1;
  int row0 = blockIdx.y * 128;
  int n0 = blockIdx.x * 128;

  int sr = t >> 2, sc = (t & 3) * 8;  // staging: row 0..63, col 0/8/16/24

  f32x4 acc[4][4];
#pragma unroll
  for (int i = 0; i < 4; ++i)
#pragma unroll
    for (int j = 0; j < 4; ++j) acc[i][j] = f32x4{0.f, 0.f, 0.f, 0.f};

  for (int k0 = 0; k0 < 512; k0 += 32) {
    f16x8 a0 = *(const f16x8*)(Xh + (size_t)(row0 + sr) * 512 + k0 + sc);
    f16x8 a1 = *(const f16x8*)(Xh + (size_t)(row0 + sr + 64) * 512 + k0 + sc);
    f16x8 b0 = *(const f16x8*)(Wt + (size_t)(n0 + sr) * 512 + k0 + sc);
    f16x8 b1 = *(const f16x8*)(Wt + (size_t)(n0 + sr + 64) * 512 + k0 + sc);
    *(f16x8*)(As + sr * 32 + sc) = a0;
    *(f16x8*)(As + (sr + 64) * 32 + sc) = a1;
    *(f16x8*)(Bs + sr * 32 + sc) = b0;
    *(f16x8*)(Bs + (sr + 64) * 32 + sc) = b1;
    __syncthreads();

    f16x8 af[4], bf[4];
#pragma unroll
    for (int m = 0; m < 4; ++m)
      af[m] = *(const f16x8*)(As + (wr * 64 + m * 16 + lc) * 32 + q * 8);
#pragma unroll
    for (int n = 0; n < 4; ++n)
      bf[n] = *(const f16x8*)(Bs + (wc * 64 + n * 16 + lc) * 32 + q * 8);
#pragma unroll
    for (int m = 0; m < 4; ++m)
#pragma unroll
      for (int n = 0; n < 4; ++n)
        acc[m][n] = __builtin_amdgcn_mfma_f32_16x16x32_f16(af[m], bf[n], acc[m][n], 0, 0, 0);
    __syncthreads();
  }

#pragma unroll
  for (int m = 0; m < 4; ++m) {
#pragma unroll
    for (int ns = 0; ns < 4; ++ns) {
      int c = n0 + wc * 64 + ns * 16 + lc;
      if (c < 1028) {
        int sub = (c >= 771) ? 3 : (c >= 514) ? 2 : (c >= 257) ? 1 : 0;
        int e = c - sub * 257;
        float bv = (sub == 0) ? lbr[e] : (sub == 1) ? lbi[e] : (sub == 2) ? hbr[e] : hbi[e];
#pragma unroll
        for (int r = 0; r < 4; ++r) {
          int row = row0 + wr * 64 + m * 16 + q * 4 + r;
          float val = fmaxf(acc[m][ns][r] + bv, 0.f) * S_FOLD;
          LHf[(size_t)row * LD16 + sub * 264 + e] = (_Float16)val;
        }
      }
    }
  }
}

// ---------------- repack K into MFMA B-frag-linear order ----------------

__global__ __launch_bounds__(256) void repack_K(
    const _Float16* __restrict__ LHf, _Float16* __restrict__ Kpack) {
  int t = threadIdx.x;
  int w = t >> 6, L = t & 63, q = L >> 4, lc = L & 15;
  int wc = blockIdx.x * 4 + w;
  int ec = wc % 9;
  int tmp = wc / 9;
  int jt = tmp & 31; tmp >>= 5;
  int comp = tmp & 1; tmp >>= 1;
  int pass = tmp & 1;
  int b = tmp >> 1;
  f16x8 v;
  if (ec == 8 && q > 0) {
    v = f16x8{(_Float16)0, (_Float16)0, (_Float16)0, (_Float16)0,
              (_Float16)0, (_Float16)0, (_Float16)0, (_Float16)0};
  } else {
    v = *(const f16x8*)(LHf + (size_t)(b * 512 + jt * 16 + lc) * LD16 +
                        pass * 528 + comp * 264 + ec * 32 + q * 8);
  }
  *(f16x8*)(Kpack + (size_t)wc * 512 + L * 8) = v;
}

// ---------------- repack V (low) into PV B-frag order via LDS transpose ----------------

__global__ __launch_bounds__(256) void repack_V(
    const _Float16* __restrict__ LHf, _Float16* __restrict__ Vpack) {
  int bid = blockIdx.x;
  int et = bid % 17;
  int tmp = bid / 17;
  int comp = tmp & 1;
  int b = tmp >> 1;
  int t = threadIdx.x;
  __shared__ __align__(16) _Float16 tile[512 * 16];

  const f16x8 zero8 = {(_Float16)0, (_Float16)0, (_Float16)0, (_Float16)0,
                       (_Float16)0, (_Float16)0, (_Float16)0, (_Float16)0};
  for (int j = t; j < 512; j += 256) {
    const _Float16* src = LHf + (size_t)(b * 512 + j) * LD16 + comp * 264 + et * 16;
    f16x8 v0, v1;
    if (et < 16) {
      v0 = *(const f16x8*)(src);
      v1 = *(const f16x8*)(src + 8);
    } else {
      v0 = *(const f16x8*)(src);
      v1 = zero8;
    }
    *(f16x8*)(tile + j * 16) = v0;
    *(f16x8*)(tile + j * 16 + 8) = v1;
  }
  __syncthreads();

#pragma unroll
  for (int it = 0; it < 4; ++it) {
    int c2 = it * 256 + t;
    int ks = c2 >> 6;
    int L2 = c2 & 63;
    int q2 = L2 >> 4, lc2 = L2 & 15;
    f16x8 v;
#pragma unroll
    for (int i = 0; i < 8; ++i) v[i] = tile[(ks * 32 + q2 * 8 + i) * 16 + lc2];
    *(f16x8*)(Vpack + ((((size_t)(b * 2 + comp) * 17 + et) * 16 + ks) * 512) + L2 * 8) = v;
  }
}

// ---------------- DPP 16-lane reductions (VALU pipe, no DS latency) ----------------

template <int CTRL>
__device__ __forceinline__ float dpp_f32(float x) {
  return __int_as_float(
      __builtin_amdgcn_update_dpp(0, __float_as_int(x), CTRL, 0xF, 0xF, true));
}

__device__ __forceinline__ float red_max16(float x) {
  x = fmaxf(x, dpp_f32<0xB1>(x));
  x = fmaxf(x, dpp_f32<0x4E>(x));
  x = fmaxf(x, dpp_f32<0x141>(x));
  x = fmaxf(x, dpp_f32<0x140>(x));
  return x;
}

__device__ __forceinline__ float red_sum16(float x) {
  x += dpp_f32<0xB1>(x);
  x += dpp_f32<0x4E>(x);
  x += dpp_f32<0x141>(x);
  x += dpp_f32<0x140>(x);
  return x;
}

// softmax tail for one chunk (plain inline fn: no lambda, no arrays -> registers)
__device__ __forceinline__ void sm_tail(
    _Float16 (*sP2)[16][4][16][8], _Float16 (*sM)[32][18], _Float16 (*sS)[32][18],
    int w, int q, int lc, int jtc, f32x4 tRR, f32x4 tII, f32x4 tRI, f32x4 tIR) {
  int jj = (jtc * 4 + w) * 16 + lc;
  int ksw = jj >> 5, qw = (jj >> 3) & 3, iw = jj & 7;
  int jtile = jtc * 4 + w;
#pragma unroll
  for (int r = 0; r < 4; ++r) {
    float vr = tRR[r] - tII[r];
    float vi = tRI[r] + tIR[r];
    _Float16 mlrh = (_Float16)red_max16(vr);
    _Float16 mlih = (_Float16)red_max16(vi);
    float ur = __expf(vr - (float)mlrh);
    float ui = __expf(vi - (float)mlih);
    int row = q * 4 + r;
    sP2[0][ksw][qw][row][iw] = (_Float16)ur;
    sP2[1][ksw][qw][row][iw] = (_Float16)ui;
    float sr = red_sum16(ur);
    float si = red_sum16(ui);
    if (lc == 0) {
      sM[0][jtile][row] = mlrh;
      sS[0][jtile][row] = (_Float16)sr;
      sM[1][jtile][row] = mlih;
      sS[1][jtile][row] = (_Float16)si;
    }
  }
}

// ---------------- MFMA f16 flash attention, DEFERRED PV, 3 blocks/CU ----------------
// Phase 1 pipelined with NAMED staging regs: 18 back-to-back Kpack loads (one L2
// latency per chunk, not 9 serial load->MFMA stalls), previous chunk's softmax
// tail runs under the latency, then 36 MFMAs consume the named frags.
// Live set (pass-1 worst case): acc 40 + staged 72 + scores 16 + Qf8 8 + addr
// ~= 150 < 170 cap of __launch_bounds__(256,3). Spill falsifier: WRITE_SIZE.

__global__ __launch_bounds__(256, 3) void attn_mfma3(
    const _Float16* __restrict__ LHf, const _Float16* __restrict__ Kpack,
    const _Float16* __restrict__ Vpack, _Float16* __restrict__ OXh) {
  int bid = blockIdx.x;
  int xcd = bid & 7;
  int ix = bid >> 3;
  int rt = ix & 31;
  int b = xcd + 8 * (ix >> 5);
  int t = threadIdx.x;
  int w = t >> 6, L = t & 63, q = L >> 4, lc = L & 15;

  __shared__ __align__(16) _Float16 sQc[2][8][64][8];      // 16384 B
  __shared__ __align__(16) _Float16 sP2[2][16][4][16][8];  // 32768 B
  __shared__ __align__(16) _Float16 sM[2][32][18];         // 2304 B
  __shared__ __align__(16) _Float16 sS[2][32][18];         // 2304 B

  const f16x8 zero8 = {(_Float16)0, (_Float16)0, (_Float16)0, (_Float16)0,
                       (_Float16)0, (_Float16)0, (_Float16)0, (_Float16)0};

  // fill sQc (chunk-linear: lane L owns slot [comp][ec][L]) + Qf8 in regs
  const _Float16* qbase = LHf + (size_t)(b * 512 + rt * 16 + lc) * LD16;
  f16x8 Qf8_0 = (q == 0) ? *(const f16x8*)(qbase + 256) : zero8;
  f16x8 Qf8_1 = (q == 0) ? *(const f16x8*)(qbase + 264 + 256) : zero8;
  for (int g = w; g < 16; g += 4) {
    int comp = g >> 3, ec = g & 7;
    f16x8 v = *(const f16x8*)(qbase + comp * 264 + ec * 32 + q * 8);
    *(f16x8*)(&sQc[comp][ec][L][0]) = v;
  }
  __syncthreads();

  int t0 = (w == 0) ? 0 : (4 * w + 1);   // et tiles {0..4},{5..8},{9..12},{13..16}
  int nt = (w == 0) ? 5 : 4;
  int h = q >> 1;

  f32x4 accR[5], accI[5];  // final normalized outputs, accumulated across passes
#pragma unroll
  for (int i = 0; i < 5; ++i) {
    accR[i] = f32x4{0.f, 0.f, 0.f, 0.f};
    accI[i] = f32x4{0.f, 0.f, 0.f, 0.f};
  }

#define QK4(q0v, q1v, krv, kiv)                                               \
  sRR = __builtin_amdgcn_mfma_f32_16x16x32_f16(q0v, krv, sRR, 0, 0, 0);       \
  sII = __builtin_amdgcn_mfma_f32_16x16x32_f16(q1v, kiv, sII, 0, 0, 0);       \
  sRI = __builtin_amdgcn_mfma_f32_16x16x32_f16(q0v, kiv, sRI, 0, 0, 0);       \
  sIR = __builtin_amdgcn_mfma_f32_16x16x32_f16(q1v, krv, sIR, 0, 0, 0);

  for (int pass = 0; pass < 2; ++pass) {
    // ========= phase 1: pipelined QK + local softmax, no barriers ======
    f32x4 sRR, sII, sRI, sIR;
    for (int jt = 0; jt < 8; ++jt) {
      const _Float16* kp0 =
          Kpack + ((((size_t)(b * 2 + pass) * 2 + 0) * 32 + (jt * 4 + w)) * 9) * 512 + L * 8;
      const _Float16* kp1 =
          Kpack + ((((size_t)(b * 2 + pass) * 2 + 1) * 32 + (jt * 4 + w)) * 9) * 512 + L * 8;
      // 18 named staged loads (back-to-back issue, single latency)
      f16x8 kr0 = *(const f16x8*)(kp0 + 0 * 512);
      f16x8 kr1 = *(const f16x8*)(kp0 + 1 * 512);
      f16x8 kr2 = *(const f16x8*)(kp0 + 2 * 512);
      f16x8 kr3 = *(const f16x8*)(kp0 + 3 * 512);
      f16x8 kr4 = *(const f16x8*)(kp0 + 4 * 512);
      f16x8 kr5 = *(const f16x8*)(kp0 + 5 * 512);
      f16x8 kr6 = *(const f16x8*)(kp0 + 6 * 512);
      f16x8 kr7 = *(const f16x8*)(kp0 + 7 * 512);
      f16x8 kr8 = *(const f16x8*)(kp0 + 8 * 512);
      f16x8 ki0 = *(const f16x8*)(kp1 + 0 * 512);
      f16x8 ki1 = *(const f16x8*)(kp1 + 1 * 512);
      f16x8 ki2 = *(const f16x8*)(kp1 + 2 * 512);
      f16x8 ki3 = *(const f16x8*)(kp1 + 3 * 512);
      f16x8 ki4 = *(const f16x8*)(kp1 + 4 * 512);
      f16x8 ki5 = *(const f16x8*)(kp1 + 5 * 512);
      f16x8 ki6 = *(const f16x8*)(kp1 + 6 * 512);
      f16x8 ki7 = *(const f16x8*)(kp1 + 7 * 512);
      f16x8 ki8 = *(const f16x8*)(kp1 + 8 * 512);
      // previous chunk's softmax tail hides the load latency
      if (jt > 0) sm_tail(sP2, sM, sS, w, q, lc, jt - 1, sRR, sII, sRI, sIR);
      sRR = f32x4{0.f, 0.f, 0.f, 0.f};
      sII = f32x4{0.f, 0.f, 0.f, 0.f};
      sRI = f32x4{0.f, 0.f, 0.f, 0.f};
      sIR = f32x4{0.f, 0.f, 0.f, 0.f};
      __builtin_amdgcn_s_setprio(1);
      {
        f16x8 q0 = *(const f16x8*)(&sQc[0][0][L][0]);
        f16x8 q1 = *(const f16x8*)(&sQc[1][0][L][0]);
        QK4(q0, q1, kr0, ki0)
      }
      {
        f16x8 q0 = *(const f16x8*)(&sQc[0][1][L][0]);
        f16x8 q1 = *(const f16x8*)(&sQc[1][1][L][0]);
        QK4(q0, q1, kr1, ki1)
      }
      {
        f16x8 q0 = *(const f16x8*)(&sQc[0][2][L][0]);
        f16x8 q1 = *(const f16x8*)(&sQc[1][2][L][0]);
        QK4(q0, q1, kr2, ki2)
      }
      {
        f16x8 q0 = *(const f16x8*)(&sQc[0][3][L][0]);
        f16x8 q1 = *(const f16x8*)(&sQc[1][3][L][0]);
        QK4(q0, q1, kr3, ki3)
      }
      {
        f16x8 q0 = *(const f16x8*)(&sQc[0][4][L][0]);
        f16x8 q1 = *(const f16x8*)(&sQc[1][4][L][0]);
        QK4(q0, q1, kr4, ki4)
      }
      {
        f16x8 q0 = *(const f16x8*)(&sQc[0][5][L][0]);
        f16x8 q1 = *(const f16x8*)(&sQc[1][5][L][0]);
        QK4(q0, q1, kr5, ki5)
      }
      {
        f16x8 q0 = *(const f16x8*)(&sQc[0][6][L][0]);
        f16x8 q1 = *(const f16x8*)(&sQc[1][6][L][0]);
        QK4(q0, q1, kr6, ki6)
      }
      {
        f16x8 q0 = *(const f16x8*)(&sQc[0][7][L][0]);
        f16x8 q1 = *(const f16x8*)(&sQc[1][7][L][0]);
        QK4(q0, q1, kr7, ki7)
      }
      { QK4(Qf8_0, Qf8_1, kr8, ki8) }
      __builtin_amdgcn_s_setprio(0);
    }
    sm_tail(sP2, sM, sS, w, q, lc, 7, sRR, sII, sRI, sIR);
    __syncthreads();  // P + stats published

    // ================= stat merge for row lc (conflict-free scalar reads) =======
    float mfR = -3.0e38f, mfI = -3.0e38f;
#pragma unroll
    for (int j = 0; j < 32; ++j) {
      mfR = fmaxf(mfR, (float)sM[0][j][lc]);
      mfI = fmaxf(mfI, (float)sM[1][j][lc]);
    }
    float lR = 0.f, lI = 0.f;
#pragma unroll
    for (int j = 0; j < 32; ++j) {
      lR += (float)sS[0][j][lc] * __expf((float)sM[0][j][lc] - mfR);
      lI += (float)sS[1][j][lc] * __expf((float)sM[1][j][lc] - mfI);
    }
    float gRb = INV_S / lR;
    float gIb = INV_S / lI;

    // ================= PV: pre-normalized A-frags, 2 accs, no barriers =========
    for (int ks = 0; ks < 16; ++ks) {
      int jtA = ks * 2 + h;
      float gR = __expf((float)sM[0][jtA][lc] - mfR) * gRb;
      float gI = __expf((float)sM[1][jtA][lc] - mfI) * gIb;
      f16x8 uR = *(const f16x8*)&sP2[0][ks][q][lc][0];
      f16x8 uI = *(const f16x8*)&sP2[1][ks][q][lc][0];
      _Float16 hR = (_Float16)gR;
      _Float16 hI = (_Float16)gI;
      _Float16 hmI = (_Float16)(-gI);
      f16x8 aR, aI, amI;
#pragma unroll
      for (int i = 0; i < 8; ++i) {
        aR[i] = uR[i] * hR;
        aI[i] = uI[i] * hI;
        amI[i] = uI[i] * hmI;
      }
      __builtin_amdgcn_s_setprio(1);
#pragma unroll
      for (int ti = 0; ti < 5; ++ti) {
        if (ti < nt) {
          int et = t0 + ti;
          size_t vb = (((size_t)(b * 2 + 0) * 17 + et) * 16 + ks) * 512;
          size_t vb2 = (((size_t)(b * 2 + 1) * 17 + et) * 16 + ks) * 512;
          f16x8 bVr = *(const f16x8*)(Vpack + vb + L * 8);
          f16x8 bVi = *(const f16x8*)(Vpack + vb2 + L * 8);
          accR[ti] = __builtin_amdgcn_mfma_f32_16x16x32_f16(aR, bVr, accR[ti], 0, 0, 0);
          accR[ti] = __builtin_amdgcn_mfma_f32_16x16x32_f16(amI, bVi, accR[ti], 0, 0, 0);
          accI[ti] = __builtin_amdgcn_mfma_f32_16x16x32_f16(aR, bVi, accI[ti], 0, 0, 0);
          accI[ti] = __builtin_amdgcn_mfma_f32_16x16x32_f16(aI, bVr, accI[ti], 0, 0, 0);
        }
      }
      __builtin_amdgcn_s_setprio(0);
    }
    __syncthreads();  // sP2/sM/sS reused by next pass's phase 1
  }
#undef QK4

  // ---- store OXh f16 rows into LHf[.][528..1056) ----
  _Float16* obase = OXh + (size_t)(b * 512 + rt * 16) * LD16 + OXOFF;
#pragma unroll
  for (int ti = 0; ti < 5; ++ti) {
    if (ti < nt) {
      int e = (t0 + ti) * 16 + lc;
      if (e < 257) {
#pragma unroll
        for (int r = 0; r < 4; ++r) {
          _Float16* dst = obase + (size_t)(q * 4 + r) * LD16;
          dst[e] = (_Float16)accR[ti][r];
          dst[264 + e] = (_Float16)accI[ti][r];
        }
      }
    }
  }
}

// ---------------- MFMA f16 GEMM: out = OXh @ iDt ----------------
// M=32768, N=512 (4 tiles of 128), K=544 (OXh pad). Register-staged f16x8;
// zero-padded tail for cols 528..543.

__global__ __launch_bounds__(256) void gemm_irfft(
    const _Float16* __restrict__ LHf, const _Float16* __restrict__ iDt,
    float* __restrict__ out) {
  __shared__ __align__(16) _Float16 As[128 * 32];
  __shared__ __align__(16) _Float16 Bs[128 * 32];

  int t = threadIdx.x;
  int w = t >> 6, L = t & 63, q = L >> 4, lc = L & 15;
  int wr = w >> 1, wc = w & 1;
  int row0 = blockIdx.y * 128;
  int n0 = blockIdx.x * 128;

  int sr = t >> 2, sc = (t & 3) * 8;

  const f16x8 zero8 = {(_Float16)0, (_Float16)0, (_Float16)0, (_Float16)0,
                       (_Float16)0, (_Float16)0, (_Float16)0, (_Float16)0};

  f32x4 acc[4][4];
#pragma unroll
  for (int i = 0; i < 4; ++i)
#pragma unroll
    for (int j = 0; j < 4; ++j) acc[i][j] = f32x4{0.f, 0.f, 0.f, 0.f};

  for (int k0 = 0; k0 < 544; k0 += 32) {
    f16x8 a0, a1;
    if (k0 + sc < 528) {
      a0 = *(const f16x8*)(LHf + (size_t)(row0 + sr) * LD16 + OXOFF + k0 + sc);
      a1 = *(const f16x8*)(LHf + (size_t)(row0 + sr + 64) * LD16 + OXOFF + k0 + sc);
    } else {
      a0 = zero8; a1 = zero8;
    }
    f16x8 b0 = *(const f16x8*)(iDt + (size_t)(n0 + sr) * 544 + k0 + sc);
    f16x8 b1 = *(const f16x8*)(iDt + (size_t)(n0 + sr + 64) * 544 + k0 + sc);
    *(f16x8*)(As + sr * 32 + sc) = a0;
    *(f16x8*)(As + (sr + 64) * 32 + sc) = a1;
    *(f16x8*)(Bs + sr * 32 + sc) = b0;
    *(f16x8*)(Bs + (sr + 64) * 32 + sc) = b1;
    __syncthreads();

    f16x8 af[4], bf[4];
#pragma unroll
    for (int m = 0; m < 4; ++m)
      af[m] = *(const f16x8*)(As + (wr * 64 + m * 16 + lc) * 32 + q * 8);
#pragma unroll
    for (int n = 0; n < 4; ++n)
      bf[n] = *(const f16x8*)(Bs + (wc * 64 + n * 16 + lc) * 32 + q * 8);
#pragma unroll
    for (int m = 0; m < 4; ++m)
#pragma unroll
      for (int n = 0; n < 4; ++n)
        acc[m][n] = __builtin_amdgcn_mfma_f32_16x16x32_f16(af[m], bf[n], acc[m][n], 0, 0, 0);
    __syncthreads();
  }

#pragma unroll
  for (int m = 0; m < 4; ++m)
#pragma unroll
    for (int ns = 0; ns < 4; ++ns) {
      int c = n0 + wc * 64 + ns * 16 + lc;
#pragma unroll
      for (int r = 0; r < 4; ++r) {
        int row = row0 + wr * 64 + m * 16 + q * 4 + r;
        out[(size_t)row * 512 + c] = acc[m][ns][r];
      }
    }
}

// ---------------- launch ----------------

extern "C" void kernel_launch(void* const* d_in, const int* in_sizes, int n_in,
                              void* d_out, int out_size, void* d_ws, size_t ws_size,
                              hipStream_t stream) {
  const float* x   = (const float*)d_in[0];
  const float* l1r = (const float*)d_in[1];
  const float* l1i = (const float*)d_in[2];
  const float* h1r = (const float*)d_in[3];
  const float* h1i = (const float*)d_in[4];
  const float* lbr = (const float*)d_in[5];
  const float* lbi = (const float*)d_in[6];
  const float* hbr = (const float*)d_in[7];
  const float* hbi = (const float*)d_in[8];
  float* out = (float*)d_out;

  _Float16* ws = (_Float16*)d_ws;
  size_t off = 0;
  _Float16* LHf = ws + off;   off += (size_t)32768 * LD16;        // 69.2 MB
  _Float16* Kpack = ws + off; off += (size_t)73728 * 512;         // 75.5 MB
  _Float16* Vpack = ws + off; off += (size_t)64 * 2 * 17 * 16 * 512;  // 35.7 MB
  _Float16* Wt = ws + off;    off += (size_t)1152 * 512;          // 1.2 MB
  _Float16* iDt = ws + off;   off += (size_t)512 * 544;           // 0.6 MB
  _Float16* Xh = Kpack;  // alias: consumed by gemm_main before repack_K overwrites

  pad_zero<<<128, 256, 0, stream>>>(LHf);
  xcast<<<2048, 256, 0, stream>>>(x, Xh);
  build_W<<<1152, 256, 0, stream>>>(l1r, l1i, h1r, h1i, Wt);
  build_idt<<<(512 * 544 + 255) / 256, 256, 0, stream>>>(iDt);

  gemm_main<<<dim3(9, 256), 256, 0, stream>>>(Xh, Wt, lbr, lbi, hbr, hbi, LHf);
  repack_K<<<73728 / 4, 256, 0, stream>>>(LHf, Kpack);
  repack_V<<<64 * 2 * 17, 256, 0, stream>>>(LHf, Vpack);
  attn_mfma3<<<2048, 256, 0, stream>>>(LHf, Kpack, Vpack, LHf);
  gemm_irfft<<<dim3(4, 256), 256, 0, stream>>>(LHf, iDt, out);
}

// Round 12
// 583.118 us; speedup vs baseline: 1.7512x; 1.6573x over previous
//
#include <hip/hip_runtime.h>
#include <math.h>

// B=64, C=512, S=512, E=257, LK=128, HK=129.
// high_x is dead code in the reference: only low_x = attn(low,low,low)+attn(low,high,low).
//
// Pipeline (5 launches; all heavy math on MFMA f16):
//  1. prologue (fused, grid-partitioned): xcast | build_W | build_idt | pad_zero
//  2. gemm_main (MFMA f16): 128x128, BK=32, register-staged f16x8
//     (global_load_lds BANNED: killed containers r7/r8)
//  3. repacks (fused): repack_K | repack_V
//  4. attn: round-9 verified structure (287us): DEFERRED PV, 3 blocks/CU,
//     per-ec load+MFMA loop. Register pipelining ABANDONED (r10/r11: spills
//     1.2GB scratch under the 170-reg cap; falsifier fired twice).
//  5. gemm_irfft (MFMA f16): 128x128, K=544, zero-padded tail.
//
// ws: LHf 69.2 MB + Kpack 75.5 MB (Xh alias) + Vpack 35.7 MB + Wt 1.2 MB + iDt 0.6 MB.

#define LD16 1056   // halves per LHf row: [lr 264 | li 264 | hr 264 | hi 264]
#define OXOFF 528   // OXh f16 output written into LHf[row][528..1056): [re 264 | im 264]

typedef __attribute__((ext_vector_type(4))) _Float16 f16x4;
typedef __attribute__((ext_vector_type(8))) _Float16 f16x8;
typedef __attribute__((ext_vector_type(4))) float f32x4;

#define S_FOLD 0.24975653f    // sqrt(1/sqrt(257))
#define INV_S  4.0039005f     // 1/S_FOLD
#define SC512  0.0441941738241592f   // 1/sqrt(512)

// ---------------- fused prologue: xcast | build_W | build_idt | pad_zero ----------
// blocks [0,2048): xcast      X f32 -> Xh f16 (grid-stride, 4 sweeps)
// blocks [2048,3200): build_W  c = bid-2048 in [0,1152)
// blocks [3200,4288): build_idt idx block
// blocks [4288,4416): pad_zero  zero the 28 pad halves per LHf row
// All four write disjoint buffers; no ordering needed among them.

__global__ __launch_bounds__(256) void prologue(
    const float* __restrict__ X, _Float16* __restrict__ Xh,
    const float* __restrict__ l1r, const float* __restrict__ l1i,
    const float* __restrict__ h1r, const float* __restrict__ h1i,
    _Float16* __restrict__ Wt, _Float16* __restrict__ iDt,
    _Float16* __restrict__ LHf) {
  __shared__ float Tc[512], Ts[512];
  __shared__ float wr[132], wi[132];
  int bid = blockIdx.x;
  int t = threadIdx.x;

  if (bid < 2048) {  // ---- xcast ----
    const size_t total = (size_t)32768 * 512;
    const size_t stride = (size_t)2048 * 256 * 8;
    for (size_t idx = ((size_t)bid * 256 + t) * 8; idx < total; idx += stride) {
      float4 a0 = *(const float4*)(X + idx);
      float4 a1 = *(const float4*)(X + idx + 4);
      f16x8 h = {(_Float16)a0.x, (_Float16)a0.y, (_Float16)a0.z, (_Float16)a0.w,
                 (_Float16)a1.x, (_Float16)a1.y, (_Float16)a1.z, (_Float16)a1.w};
      *(f16x8*)(Xh + idx) = h;
    }
    return;
  }
  if (bid < 3200) {  // ---- build_W ----
    int c = bid - 2048;
    if (c >= 1028) {
      for (int n = t; n < 512; n += 256) Wt[(size_t)c * 512 + n] = (_Float16)0.0f;
      return;
    }
    for (int i = t; i < 512; i += 256) {
      float ang = (float)i * 0.0122718463030851f;  // 2*pi/512
      Tc[i] = cosf(ang);
      Ts[i] = sinf(ang);
    }
    int sub = (c >= 771) ? 3 : (c >= 514) ? 2 : (c >= 257) ? 1 : 0;
    int e = c - sub * 257;
    int Kn = (sub < 2) ? 128 : 129;
    int kb = (sub < 2) ? 0 : 128;
    if (t < Kn) {
      if (sub < 2) { wr[t] = l1r[t * 257 + e]; wi[t] = l1i[t * 257 + e]; }
      else         { wr[t] = h1r[t * 257 + e]; wi[t] = h1i[t * 257 + e]; }
    }
    __syncthreads();
    bool imag_out = (sub & 1);
    for (int n = t; n < 512; n += 256) {
      float acc = 0.f;
      for (int k = 0; k < Kn; ++k) {
        int kk = kb + k;
        int m = (n * kk) & 511;
        float Fr = Tc[m] * SC512;
        float Fi = -Ts[m] * SC512;
        if (!imag_out) acc += Fr * wr[k] - Fi * wi[k];
        else           acc += Fr * wi[k] + Fi * wr[k];
      }
      Wt[(size_t)c * 512 + n] = (_Float16)acc;
    }
    return;
  }
  if (bid < 4288) {  // ---- build_idt ----
    int idx = (bid - 3200) * 256 + t;
    const int total = 512 * 544;
    if (idx >= total) return;
    int n = idx / 544;
    int k = idx - n * 544;
    float val = 0.f;
    if (k < 264) {
      int e = k;
      if (e <= 256) {
        float ce = (e == 0 || e == 256) ? 1.f : 2.f;
        int m = (n * e) & 511;
        val = ce * SC512 * cosf((float)m * 0.0122718463030851f);
      }
    } else if (k < 528) {
      int e = k - 264;
      if (e <= 256) {
        float ce = (e == 0 || e == 256) ? 1.f : 2.f;
        int m = (n * e) & 511;
        val = -ce * SC512 * sinf((float)m * 0.0122718463030851f);
      }
    }
    iDt[(size_t)n * 544 + k] = (_Float16)val;
    return;
  }
  {  // ---- pad_zero: e=257..263 in each 264-wide sub-block ----
    int row = (bid - 4288) * 256 + t;
    _Float16* p = LHf + (size_t)row * LD16;
#pragma unroll
    for (int sub = 0; sub < 4; ++sub)
#pragma unroll
      for (int e = 257; e < 264; ++e) p[sub * 264 + e] = (_Float16)0;
  }
}

// ---------------- MFMA f16 GEMM: LHf = relu(Xh @ W + bias) * S_FOLD ----------------
// M=32768, N=1152 (9 tiles of 128, c>=1028 discarded), K=512, BK=32.

__global__ __launch_bounds__(256) void gemm_main(
    const _Float16* __restrict__ Xh, const _Float16* __restrict__ Wt,
    const float* __restrict__ lbr, const float* __restrict__ lbi,
    const float* __restrict__ hbr, const float* __restrict__ hbi,
    _Float16* __restrict__ LHf) {
  __shared__ __align__(16) _Float16 As[128 * 32];
  __shared__ __align__(16) _Float16 Bs[128 * 32];

  int t = threadIdx.x;
  int w = t >> 6, L = t & 63, q = L >> 4, lc = L & 15;
  int wr = w >> 1, wc = w & 1;
  int row0 = blockIdx.y * 128;
  int n0 = blockIdx.x * 128;

  int sr = t >> 2, sc = (t & 3) * 8;  // staging: row 0..63, col 0/8/16/24

  f32x4 acc[4][4];
#pragma unroll
  for (int i = 0; i < 4; ++i)
#pragma unroll
    for (int j = 0; j < 4; ++j) acc[i][j] = f32x4{0.f, 0.f, 0.f, 0.f};

  for (int k0 = 0; k0 < 512; k0 += 32) {
    f16x8 a0 = *(const f16x8*)(Xh + (size_t)(row0 + sr) * 512 + k0 + sc);
    f16x8 a1 = *(const f16x8*)(Xh + (size_t)(row0 + sr + 64) * 512 + k0 + sc);
    f16x8 b0 = *(const f16x8*)(Wt + (size_t)(n0 + sr) * 512 + k0 + sc);
    f16x8 b1 = *(const f16x8*)(Wt + (size_t)(n0 + sr + 64) * 512 + k0 + sc);
    *(f16x8*)(As + sr * 32 + sc) = a0;
    *(f16x8*)(As + (sr + 64) * 32 + sc) = a1;
    *(f16x8*)(Bs + sr * 32 + sc) = b0;
    *(f16x8*)(Bs + (sr + 64) * 32 + sc) = b1;
    __syncthreads();

    f16x8 af[4], bf[4];
#pragma unroll
    for (int m = 0; m < 4; ++m)
      af[m] = *(const f16x8*)(As + (wr * 64 + m * 16 + lc) * 32 + q * 8);
#pragma unroll
    for (int n = 0; n < 4; ++n)
      bf[n] = *(const f16x8*)(Bs + (wc * 64 + n * 16 + lc) * 32 + q * 8);
#pragma unroll
    for (int m = 0; m < 4; ++m)
#pragma unroll
      for (int n = 0; n < 4; ++n)
        acc[m][n] = __builtin_amdgcn_mfma_f32_16x16x32_f16(af[m], bf[n], acc[m][n], 0, 0, 0);
    __syncthreads();
  }

#pragma unroll
  for (int m = 0; m < 4; ++m) {
#pragma unroll
    for (int ns = 0; ns < 4; ++ns) {
      int c = n0 + wc * 64 + ns * 16 + lc;
      if (c < 1028) {
        int sub = (c >= 771) ? 3 : (c >= 514) ? 2 : (c >= 257) ? 1 : 0;
        int e = c - sub * 257;
        float bv = (sub == 0) ? lbr[e] : (sub == 1) ? lbi[e] : (sub == 2) ? hbr[e] : hbi[e];
#pragma unroll
        for (int r = 0; r < 4; ++r) {
          int row = row0 + wr * 64 + m * 16 + q * 4 + r;
          float val = fmaxf(acc[m][ns][r] + bv, 0.f) * S_FOLD;
          LHf[(size_t)row * LD16 + sub * 264 + e] = (_Float16)val;
        }
      }
    }
  }
}

// ---------------- fused repacks: repack_K | repack_V ----------------
// blocks [0,18432): repack_K ; blocks [18432,20608): repack_V.

__global__ __launch_bounds__(256) void repacks(
    const _Float16* __restrict__ LHf, _Float16* __restrict__ Kpack,
    _Float16* __restrict__ Vpack) {
  __shared__ __align__(16) _Float16 tile[512 * 16];
  int t = threadIdx.x;

  if (blockIdx.x < 18432) {  // ---- repack_K ----
    int w = t >> 6, L = t & 63, q = L >> 4, lc = L & 15;
    int wc = blockIdx.x * 4 + w;
    int ec = wc % 9;
    int tmp = wc / 9;
    int jt = tmp & 31; tmp >>= 5;
    int comp = tmp & 1; tmp >>= 1;
    int pass = tmp & 1;
    int b = tmp >> 1;
    f16x8 v;
    if (ec == 8 && q > 0) {
      v = f16x8{(_Float16)0, (_Float16)0, (_Float16)0, (_Float16)0,
                (_Float16)0, (_Float16)0, (_Float16)0, (_Float16)0};
    } else {
      v = *(const f16x8*)(LHf + (size_t)(b * 512 + jt * 16 + lc) * LD16 +
                          pass * 528 + comp * 264 + ec * 32 + q * 8);
    }
    *(f16x8*)(Kpack + (size_t)wc * 512 + L * 8) = v;
    return;
  }

  // ---- repack_V ----
  int bid = blockIdx.x - 18432;
  int et = bid % 17;
  int tmp = bid / 17;
  int comp = tmp & 1;
  int b = tmp >> 1;

  const f16x8 zero8 = {(_Float16)0, (_Float16)0, (_Float16)0, (_Float16)0,
                       (_Float16)0, (_Float16)0, (_Float16)0, (_Float16)0};
  for (int j = t; j < 512; j += 256) {
    const _Float16* src = LHf + (size_t)(b * 512 + j) * LD16 + comp * 264 + et * 16;
    f16x8 v0, v1;
    if (et < 16) {
      v0 = *(const f16x8*)(src);
      v1 = *(const f16x8*)(src + 8);
    } else {
      v0 = *(const f16x8*)(src);
      v1 = zero8;
    }
    *(f16x8*)(tile + j * 16) = v0;
    *(f16x8*)(tile + j * 16 + 8) = v1;
  }
  __syncthreads();

#pragma unroll
  for (int it = 0; it < 4; ++it) {
    int c2 = it * 256 + t;
    int ks = c2 >> 6;
    int L2 = c2 & 63;
    int q2 = L2 >> 4, lc2 = L2 & 15;
    f16x8 v;
#pragma unroll
    for (int i = 0; i < 8; ++i) v[i] = tile[(ks * 32 + q2 * 8 + i) * 16 + lc2];
    *(f16x8*)(Vpack + ((((size_t)(b * 2 + comp) * 17 + et) * 16 + ks) * 512) + L2 * 8) = v;
  }
}

// ---------------- DPP 16-lane reductions (VALU pipe, no DS latency) ----------------

template <int CTRL>
__device__ __forceinline__ float dpp_f32(float x) {
  return __int_as_float(
      __builtin_amdgcn_update_dpp(0, __float_as_int(x), CTRL, 0xF, 0xF, true));
}

__device__ __forceinline__ float red_max16(float x) {
  x = fmaxf(x, dpp_f32<0xB1>(x));
  x = fmaxf(x, dpp_f32<0x4E>(x));
  x = fmaxf(x, dpp_f32<0x141>(x));
  x = fmaxf(x, dpp_f32<0x140>(x));
  return x;
}

__device__ __forceinline__ float red_sum16(float x) {
  x += dpp_f32<0xB1>(x);
  x += dpp_f32<0x4E>(x);
  x += dpp_f32<0x141>(x);
  x += dpp_f32<0x140>(x);
  return x;
}

// ---------------- MFMA f16 flash attention, DEFERRED PV, 3 blocks/CU ----------------
// (round-9 verified structure, unchanged: ~287us, MfmaUtil 22%, Occ 31%, no spill)

__global__ __launch_bounds__(256, 3) void attn_mfma3(
    const _Float16* __restrict__ LHf, const _Float16* __restrict__ Kpack,
    const _Float16* __restrict__ Vpack, _Float16* __restrict__ OXh) {
  int bid = blockIdx.x;
  int xcd = bid & 7;
  int ix = bid >> 3;
  int rt = ix & 31;
  int b = xcd + 8 * (ix >> 5);
  int t = threadIdx.x;
  int w = t >> 6, L = t & 63, q = L >> 4, lc = L & 15;

  __shared__ __align__(16) _Float16 sQc[2][8][64][8];      // 16384 B
  __shared__ __align__(16) _Float16 sP2[2][16][4][16][8];  // 32768 B
  __shared__ __align__(16) _Float16 sM[2][32][18];         // 2304 B
  __shared__ __align__(16) _Float16 sS[2][32][18];         // 2304 B

  const f16x8 zero8 = {(_Float16)0, (_Float16)0, (_Float16)0, (_Float16)0,
                       (_Float16)0, (_Float16)0, (_Float16)0, (_Float16)0};

  // fill sQc (chunk-linear: lane L owns slot [comp][ec][L]) + Qf8 in regs
  const _Float16* qbase = LHf + (size_t)(b * 512 + rt * 16 + lc) * LD16;
  f16x8 Qf8[2];
#pragma unroll
  for (int comp = 0; comp < 2; ++comp)
    Qf8[comp] = (q == 0) ? *(const f16x8*)(qbase + comp * 264 + 256) : zero8;
  for (int g = w; g < 16; g += 4) {
    int comp = g >> 3, ec = g & 7;
    f16x8 v = *(const f16x8*)(qbase + comp * 264 + ec * 32 + q * 8);
    *(f16x8*)(&sQc[comp][ec][L][0]) = v;
  }
  __syncthreads();

  int t0 = (w == 0) ? 0 : (4 * w + 1);   // et tiles {0..4},{5..8},{9..12},{13..16}
  int nt = (w == 0) ? 5 : 4;
  int h = q >> 1;

  f32x4 accR[5], accI[5];  // final normalized outputs, accumulated across passes
#pragma unroll
  for (int i = 0; i < 5; ++i) {
    accR[i] = f32x4{0.f, 0.f, 0.f, 0.f};
    accI[i] = f32x4{0.f, 0.f, 0.f, 0.f};
  }

  for (int pass = 0; pass < 2; ++pass) {
    // ================= phase 1: QK + local softmax, no barriers =================
    for (int jt = 0; jt < 8; ++jt) {
      size_t kb0 = ((((size_t)(b * 2 + pass) * 2 + 0) * 32 + (jt * 4 + w)) * 9) * 512;
      size_t kb1 = ((((size_t)(b * 2 + pass) * 2 + 1) * 32 + (jt * 4 + w)) * 9) * 512;
      f32x4 sRR = f32x4{0.f, 0.f, 0.f, 0.f};
      f32x4 sII = f32x4{0.f, 0.f, 0.f, 0.f};
      f32x4 sRI = f32x4{0.f, 0.f, 0.f, 0.f};
      f32x4 sIR = f32x4{0.f, 0.f, 0.f, 0.f};
      __builtin_amdgcn_s_setprio(1);
#pragma unroll
      for (int ec = 0; ec < 8; ++ec) {
        f16x8 bKr = *(const f16x8*)(Kpack + kb0 + (size_t)ec * 512 + L * 8);
        f16x8 bKi = *(const f16x8*)(Kpack + kb1 + (size_t)ec * 512 + L * 8);
        f16x8 q0 = *(const f16x8*)(&sQc[0][ec][L][0]);
        f16x8 q1 = *(const f16x8*)(&sQc[1][ec][L][0]);
        sRR = __builtin_amdgcn_mfma_f32_16x16x32_f16(q0, bKr, sRR, 0, 0, 0);
        sII = __builtin_amdgcn_mfma_f32_16x16x32_f16(q1, bKi, sII, 0, 0, 0);
        sRI = __builtin_amdgcn_mfma_f32_16x16x32_f16(q0, bKi, sRI, 0, 0, 0);
        sIR = __builtin_amdgcn_mfma_f32_16x16x32_f16(q1, bKr, sIR, 0, 0, 0);
      }
      {  // ec == 8 (Q fragment in registers)
        f16x8 bKr = *(const f16x8*)(Kpack + kb0 + (size_t)8 * 512 + L * 8);
        f16x8 bKi = *(const f16x8*)(Kpack + kb1 + (size_t)8 * 512 + L * 8);
        sRR = __builtin_amdgcn_mfma_f32_16x16x32_f16(Qf8[0], bKr, sRR, 0, 0, 0);
        sII = __builtin_amdgcn_mfma_f32_16x16x32_f16(Qf8[1], bKi, sII, 0, 0, 0);
        sRI = __builtin_amdgcn_mfma_f32_16x16x32_f16(Qf8[0], bKi, sRI, 0, 0, 0);
        sIR = __builtin_amdgcn_mfma_f32_16x16x32_f16(Qf8[1], bKr, sIR, 0, 0, 0);
      }
      __builtin_amdgcn_s_setprio(0);

      int jj = (jt * 4 + w) * 16 + lc;
      int ksw = jj >> 5, qw = (jj >> 3) & 3, iw = jj & 7;
      int jtile = jt * 4 + w;
#pragma unroll
      for (int r = 0; r < 4; ++r) {
        float vr = sRR[r] - sII[r];
        float vi = sRI[r] + sIR[r];
        _Float16 mlrh = (_Float16)red_max16(vr);
        _Float16 mlih = (_Float16)red_max16(vi);
        float mlr = (float)mlrh;
        float mli = (float)mlih;
        float ur = __expf(vr - mlr);
        float ui = __expf(vi - mli);
        int row = q * 4 + r;
        sP2[0][ksw][qw][row][iw] = (_Float16)ur;
        sP2[1][ksw][qw][row][iw] = (_Float16)ui;
        float sr = red_sum16(ur);
        float si = red_sum16(ui);
        if (lc == 0) {
          sM[0][jtile][row] = mlrh;
          sS[0][jtile][row] = (_Float16)sr;
          sM[1][jtile][row] = mlih;
          sS[1][jtile][row] = (_Float16)si;
        }
      }
    }
    __syncthreads();  // P + stats published

    // ================= stat merge for row lc (conflict-free scalar reads) =======
    float mfR = -3.0e38f, mfI = -3.0e38f;
#pragma unroll
    for (int j = 0; j < 32; ++j) {
      mfR = fmaxf(mfR, (float)sM[0][j][lc]);
      mfI = fmaxf(mfI, (float)sM[1][j][lc]);
    }
    float lR = 0.f, lI = 0.f;
#pragma unroll
    for (int j = 0; j < 32; ++j) {
      lR += (float)sS[0][j][lc] * __expf((float)sM[0][j][lc] - mfR);
      lI += (float)sS[1][j][lc] * __expf((float)sM[1][j][lc] - mfI);
    }
    float gRb = INV_S / lR;
    float gIb = INV_S / lI;

    // ================= PV: pre-normalized A-frags, 2 accs, no barriers =========
    for (int ks = 0; ks < 16; ++ks) {
      int jtA = ks * 2 + h;
      float gR = __expf((float)sM[0][jtA][lc] - mfR) * gRb;
      float gI = __expf((float)sM[1][jtA][lc] - mfI) * gIb;
      f16x8 uR = *(const f16x8*)&sP2[0][ks][q][lc][0];
      f16x8 uI = *(const f16x8*)&sP2[1][ks][q][lc][0];
      _Float16 hR = (_Float16)gR;
      _Float16 hI = (_Float16)gI;
      _Float16 hmI = (_Float16)(-gI);
      f16x8 aR, aI, amI;
#pragma unroll
      for (int i = 0; i < 8; ++i) {
        aR[i] = uR[i] * hR;
        aI[i] = uI[i] * hI;
        amI[i] = uI[i] * hmI;
      }
      __builtin_amdgcn_s_setprio(1);
#pragma unroll
      for (int ti = 0; ti < 5; ++ti) {
        if (ti < nt) {
          int et = t0 + ti;
          size_t vb = (((size_t)(b * 2 + 0) * 17 + et) * 16 + ks) * 512;
          size_t vb2 = (((size_t)(b * 2 + 1) * 17 + et) * 16 + ks) * 512;
          f16x8 bVr = *(const f16x8*)(Vpack + vb + L * 8);
          f16x8 bVi = *(const f16x8*)(Vpack + vb2 + L * 8);
          accR[ti] = __builtin_amdgcn_mfma_f32_16x16x32_f16(aR, bVr, accR[ti], 0, 0, 0);
          accR[ti] = __builtin_amdgcn_mfma_f32_16x16x32_f16(amI, bVi, accR[ti], 0, 0, 0);
          accI[ti] = __builtin_amdgcn_mfma_f32_16x16x32_f16(aR, bVi, accI[ti], 0, 0, 0);
          accI[ti] = __builtin_amdgcn_mfma_f32_16x16x32_f16(aI, bVr, accI[ti], 0, 0, 0);
        }
      }
      __builtin_amdgcn_s_setprio(0);
    }
    __syncthreads();  // sP2/sM/sS reused by next pass's phase 1
  }

  // ---- store OXh f16 rows into LHf[.][528..1056) ----
  _Float16* obase = OXh + (size_t)(b * 512 + rt * 16) * LD16 + OXOFF;
#pragma unroll
  for (int ti = 0; ti < 5; ++ti) {
    if (ti < nt) {
      int e = (t0 + ti) * 16 + lc;
      if (e < 257) {
#pragma unroll
        for (int r = 0; r < 4; ++r) {
          _Float16* dst = obase + (size_t)(q * 4 + r) * LD16;
          dst[e] = (_Float16)accR[ti][r];
          dst[264 + e] = (_Float16)accI[ti][r];
        }
      }
    }
  }
}

// ---------------- MFMA f16 GEMM: out = OXh @ iDt ----------------
// M=32768, N=512 (4 tiles of 128), K=544 (OXh pad). Register-staged f16x8;
// zero-padded tail for cols 528..543.

__global__ __launch_bounds__(256) void gemm_irfft(
    const _Float16* __restrict__ LHf, const _Float16* __restrict__ iDt,
    float* __restrict__ out) {
  __shared__ __align__(16) _Float16 As[128 * 32];
  __shared__ __align__(16) _Float16 Bs[128 * 32];

  int t = threadIdx.x;
  int w = t >> 6, L = t & 63, q = L >> 4, lc = L & 15;
  int wr = w >> 1, wc = w & 1;
  int row0 = blockIdx.y * 128;
  int n0 = blockIdx.x * 128;

  int sr = t >> 2, sc = (t & 3) * 8;

  const f16x8 zero8 = {(_Float16)0, (_Float16)0, (_Float16)0, (_Float16)0,
                       (_Float16)0, (_Float16)0, (_Float16)0, (_Float16)0};

  f32x4 acc[4][4];
#pragma unroll
  for (int i = 0; i < 4; ++i)
#pragma unroll
    for (int j = 0; j < 4; ++j) acc[i][j] = f32x4{0.f, 0.f, 0.f, 0.f};

  for (int k0 = 0; k0 < 544; k0 += 32) {
    f16x8 a0, a1;
    if (k0 + sc < 528) {
      a0 = *(const f16x8*)(LHf + (size_t)(row0 + sr) * LD16 + OXOFF + k0 + sc);
      a1 = *(const f16x8*)(LHf + (size_t)(row0 + sr + 64) * LD16 + OXOFF + k0 + sc);
    } else {
      a0 = zero8; a1 = zero8;
    }
    f16x8 b0 = *(const f16x8*)(iDt + (size_t)(n0 + sr) * 544 + k0 + sc);
    f16x8 b1 = *(const f16x8*)(iDt + (size_t)(n0 + sr + 64) * 544 + k0 + sc);
    *(f16x8*)(As + sr * 32 + sc) = a0;
    *(f16x8*)(As + (sr + 64) * 32 + sc) = a1;
    *(f16x8*)(Bs + sr * 32 + sc) = b0;
    *(f16x8*)(Bs + (sr + 64) * 32 + sc) = b1;
    __syncthreads();

    f16x8 af[4], bf[4];
#pragma unroll
    for (int m = 0; m < 4; ++m)
      af[m] = *(const f16x8*)(As + (wr * 64 + m * 16 + lc) * 32 + q * 8);
#pragma unroll
    for (int n = 0; n < 4; ++n)
      bf[n] = *(const f16x8*)(Bs + (wc * 64 + n * 16 + lc) * 32 + q * 8);
#pragma unroll
    for (int m = 0; m < 4; ++m)
#pragma unroll
      for (int n = 0; n < 4; ++n)
        acc[m][n] = __builtin_amdgcn_mfma_f32_16x16x32_f16(af[m], bf[n], acc[m][n], 0, 0, 0);
    __syncthreads();
  }

#pragma unroll
  for (int m = 0; m < 4; ++m)
#pragma unroll
    for (int ns = 0; ns < 4; ++ns) {
      int c = n0 + wc * 64 + ns * 16 + lc;
#pragma unroll
      for (int r = 0; r < 4; ++r) {
        int row = row0 + wr * 64 + m * 16 + q * 4 + r;
        out[(size_t)row * 512 + c] = acc[m][ns][r];
      }
    }
}

// ---------------- launch ----------------

extern "C" void kernel_launch(void* const* d_in, const int* in_sizes, int n_in,
                              void* d_out, int out_size, void* d_ws, size_t ws_size,
                              hipStream_t stream) {
  const float* x   = (const float*)d_in[0];
  const float* l1r = (const float*)d_in[1];
  const float* l1i = (const float*)d_in[2];
  const float* h1r = (const float*)d_in[3];
  const float* h1i = (const float*)d_in[4];
  const float* lbr = (const float*)d_in[5];
  const float* lbi = (const float*)d_in[6];
  const float* hbr = (const float*)d_in[7];
  const float* hbi = (const float*)d_in[8];
  float* out = (float*)d_out;

  _Float16* ws = (_Float16*)d_ws;
  size_t off = 0;
  _Float16* LHf = ws + off;   off += (size_t)32768 * LD16;        // 69.2 MB
  _Float16* Kpack = ws + off; off += (size_t)73728 * 512;         // 75.5 MB
  _Float16* Vpack = ws + off; off += (size_t)64 * 2 * 17 * 16 * 512;  // 35.7 MB
  _Float16* Wt = ws + off;    off += (size_t)1152 * 512;          // 1.2 MB
  _Float16* iDt = ws + off;   off += (size_t)512 * 544;           // 0.6 MB
  _Float16* Xh = Kpack;  // alias: consumed by gemm_main before repacks overwrite

  prologue<<<4416, 256, 0, stream>>>(x, Xh, l1r, l1i, h1r, h1i, Wt, iDt, LHf);
  gemm_main<<<dim3(9, 256), 256, 0, stream>>>(Xh, Wt, lbr, lbi, hbr, hbi, LHf);
  repacks<<<20608, 256, 0, stream>>>(LHf, Kpack, Vpack);
  attn_mfma3<<<2048, 256, 0, stream>>>(LHf, Kpack, Vpack, LHf);
  gemm_irfft<<<dim3(4, 256), 256, 0, stream>>>(LHf, iDt, out);
}